// Round 1
// baseline (66.547 us; speedup 1.0000x reference)
//
#include <hip/hip_runtime.h>

// Problem constants: N=375 pictures, C=5 channels, F=64 features, D=13 token dim.
// IDX rows start at {0,12,25,38,51}, each 13 long (rows 0 and 1 overlap at f=12,
// but the scatter targets different output rows, so no collision).

__global__ __launch_bounds__(64) void token_kernel(
    const float* __restrict__ picture,
    const float* __restrict__ t0, const float* __restrict__ t1,
    const float* __restrict__ t2, const float* __restrict__ t3,
    const float* __restrict__ t4,
    float* __restrict__ out)
{
    const int n = blockIdx.x;   // picture index, 0..374
    const int t = threadIdx.x;  // 0..63 (exactly one wave)

    __shared__ float T[5][13];     // stacked tokens
    __shared__ float pic[5][64];   // picture[n]
    __shared__ float Dm[5][5];     // cost matrix (rows=channel c, cols=token s)
    __shared__ float fullsq[5];
    __shared__ int   assign[5];

    // ---- load tokens (65 floats) ----
    const float* toks[5] = {t0, t1, t2, t3, t4};
    for (int i = t; i < 65; i += 64) {
        int s = i / 13, j = i % 13;
        T[s][j] = toks[s][j];
    }

    // ---- load picture row n (320 contiguous floats, coalesced) ----
    const float* p = picture + n * 320;
    float v[5];
#pragma unroll
    for (int c = 0; c < 5; ++c) {
        v[c] = p[c * 64 + t];
        pic[c][t] = v[c];
    }

    // ---- full_sq[c] = sum_f picture[n,c,f]^2 via wave64 shuffle reduction ----
#pragma unroll
    for (int c = 0; c < 5; ++c) {
        float s = v[c] * v[c];
#pragma unroll
        for (int off = 32; off > 0; off >>= 1)
            s += __shfl_down(s, off, 64);
        if (t == 0) fullsq[c] = s;
    }
    __syncthreads();

    // ---- Dmat: thread t<25 handles (c,s); keep reference's exact float order:
    //      (full_sq - seg_sq) + diff_sq, sums accumulated j=0..12 sequentially.
    if (t < 25) {
        int c = t / 5, s = t % 5;
        int start = (s == 0) ? 0 : (s == 1) ? 12 : (s == 2) ? 25 : (s == 3) ? 38 : 51;
        float segsq = 0.f, diffsq = 0.f;
        for (int j = 0; j < 13; ++j) {
            float x = pic[c][start + j];
            float d = x - T[s][j];
            segsq  += x * x;
            diffsq += d * d;
        }
        Dm[c][s] = (fullsq[c] - segsq) + diffsq;
    }
    __syncthreads();

    // ---- greedy assignment (serial on lane 0; 5 iters x 25 scan is trivial).
    //      Strict '<' in row-major scan == jnp.argmin first-flat-index tiebreak.
    if (t == 0) {
        bool rm[5] = {true, true, true, true, true};
        bool cm[5] = {true, true, true, true, true};
        for (int it = 0; it < 5; ++it) {
            float best = 1e30f;
            int br = 0, bc = 0;
            for (int r = 0; r < 5; ++r) {
                if (!rm[r]) continue;
                for (int c = 0; c < 5; ++c) {
                    if (!cm[c]) continue;
                    float val = Dm[r][c];
                    if (val < best) { best = val; br = r; bc = c; }
                }
            }
            assign[br] = bc;
            rm[br] = false;
            cm[bc] = false;
        }
    }
    __syncthreads();

    // ---- output: out[n,r,f] = T[assign[r]][f-start_r] if f in segment r, else 0.
    //      Writes ALL 320 elements (d_out is poisoned before each launch).
    float* o = out + n * 320;
    const int starts[5] = {0, 12, 25, 38, 51};
#pragma unroll
    for (int r = 0; r < 5; ++r) {
        int j = t - starts[r];
        float val = (j >= 0 && j < 13) ? T[assign[r]][j] : 0.f;
        o[r * 64 + t] = val;
    }
}

extern "C" void kernel_launch(void* const* d_in, const int* in_sizes, int n_in,
                              void* d_out, int out_size, void* d_ws, size_t ws_size,
                              hipStream_t stream) {
    const float* picture = (const float*)d_in[0];
    token_kernel<<<dim3(375), dim3(64), 0, stream>>>(
        picture,
        (const float*)d_in[1], (const float*)d_in[2], (const float*)d_in[3],
        (const float*)d_in[4], (const float*)d_in[5],
        (float*)d_out);
}